// Round 22
// baseline (638.565 us; speedup 1.0000x reference)
//
#include <hip/hip_runtime.h>
#include <math.h>

#define LOG2E 1.4426950408889634f

#if __has_builtin(__builtin_amdgcn_exp2f)
#define EXP2(x) __builtin_amdgcn_exp2f(x)
#else
#define EXP2(x) exp2f(x)
#endif

constexpr int B_ = 4, N_ = 2048, H_ = 4, D_ = 32, HD_ = 128;
constexpr int BH_ = B_ * H_;          // 16
constexpr int ROWS_ = BH_ * N_;       // 32768
constexpr size_t M_ = (size_t)ROWS_ * D_;  // 1,048,576 floats

// x[BN,K] @ Wl/Wr[K,128] + bl/br -> xl, xrf (both f32 [bh][n][d])
__global__ __launch_bounds__(256) void k_linear(
    const float* __restrict__ x,
    const float* __restrict__ Wl, const float* __restrict__ bl,
    const float* __restrict__ Wr, const float* __restrict__ br,
    float* __restrict__ xl, float* __restrict__ xrf, int K)
{
    __shared__ __align__(16) float xs[32 * 128];
    const int tid = threadIdx.x;
    const int r0 = blockIdx.x * 32;
    const float4* src = (const float4*)(x + (size_t)r0 * K);
    float4* dst = (float4*)xs;
    for (int idx = tid; idx < 8 * K; idx += 256) dst[idx] = src[idx];
    __syncthreads();

    const int c  = tid & 127;
    const int rg = tid >> 7;
    float accl[16], accr[16];
    const float blv = bl[c], brv = br[c];
    #pragma unroll
    for (int r = 0; r < 16; r++) { accl[r] = blv; accr[r] = brv; }
    #pragma unroll 8
    for (int k = 0; k < K; k++) {
        const float wl = Wl[k * HD_ + c];
        const float wr = Wr[k * HD_ + c];
        #pragma unroll
        for (int r = 0; r < 16; r++) {
            const float xv = xs[(rg * 16 + r) * K + k];
            accl[r] = fmaf(xv, wl, accl[r]);
            accr[r] = fmaf(xv, wr, accr[r]);
        }
    }
    const int h = c >> 5, d = c & 31;
    #pragma unroll
    for (int r = 0; r < 16; r++) {
        const int row = r0 + rg * 16 + r;
        const int b = row >> 11, n = row & (N_ - 1);
        const size_t o = (((size_t)(b * H_ + h)) * N_ + n) * D_ + d;
        xl[o] = accl[r];
        xrf[o] = accr[r];
    }
}

// u_j = 0.6*log2e * att_h . xl_j  (target-side term cancels in softmax)
__global__ __launch_bounds__(256) void k_u(
    const float* __restrict__ xl, const float* __restrict__ att,
    float* __restrict__ u)
{
    const int idx = blockIdx.x * 256 + threadIdx.x; // [0, ROWS_)
    const int h = (idx / N_) & (H_ - 1);
    const float4* a4 = (const float4*)(att + h * D_);
    const float4* l4 = (const float4*)(xl + (size_t)idx * D_);
    float su = 0.f;
    #pragma unroll
    for (int q = 0; q < 8; q++) {
        const float4 a = a4[q], lv = l4[q];
        su += a.x * lv.x + a.y * lv.y + a.z * lv.z + a.w * lv.w;
    }
    u[idx] = 0.6f * LOG2E * su;
}

// Per-row sound upper bound on e (log2 domain), all f32:
// bound_i = umax + sum_d |tc_d| (max_j|xl_jd| + |xr_id|) + slack.
__global__ __launch_bounds__(512) void k_bound(
    const float* __restrict__ xl, const float* __restrict__ xrf,
    const float* __restrict__ u, const float* __restrict__ att,
    float* __restrict__ bound)
{
    __shared__ float tca[32];
    __shared__ float redA[32][17];
    __shared__ float clv[32];
    __shared__ float redu[512];
    const int bh = blockIdx.x, h = bh & (H_ - 1), t = threadIdx.x;

    if (t < 32) tca[t] = fabsf(0.4f * LOG2E * att[h * D_ + t]);

    // cl_d = max_j |xl_jd|
    const float* xb = xl + (size_t)bh * N_ * D_;
    const int p = t & 31, rg = t >> 5;            // 32 dims x 16 row-groups
    float m0 = 0.f;
    for (int r = rg; r < N_; r += 16)
        m0 = fmaxf(m0, fabsf(xb[r * D_ + p]));
    redA[p][rg] = m0;
    // umax
    const float* ub = u + (size_t)bh * N_;
    float um = -1e30f;
    for (int r = t; r < N_; r += 512) um = fmaxf(um, ub[r]);
    redu[t] = um;
    __syncthreads();
    if (t < 32) {
        float a = 0.f;
        for (int g = 0; g < 16; g++) a = fmaxf(a, redA[t][g]);
        clv[t] = a;
    }
    for (int s = 256; s > 0; s >>= 1) {
        if (t < s) redu[t] = fmaxf(redu[t], redu[t + s]);
        __syncthreads();
    }
    const float umax = redu[0];
    const float* xrb = xrf + (size_t)bh * N_ * D_;
    for (int r = t; r < N_; r += 512) {
        float s = 0.f;
        #pragma unroll
        for (int k = 0; k < 32; k++)
            s = fmaf(tca[k], clv[k] + fabsf(xrb[r * D_ + k]), s);
        bound[bh * N_ + r] = umax + s + 0.25f;
    }
}

// ALL-F32 flash GATv2 attention. R21 post-mortem: every f16-input MAC
// (v_dot2_f32_f16 ~7-8cyc, v_fma_mix_f32 ~5-6cyc) is quarter/third rate on
// this part -- they were the 160-230us plateau across R12-R21. Plain
// v_add_f32 / v_fma_f32 are full-rate (2cyc) and VOP3 abs() is a free
// input modifier. Score: z=S+xr; e=fma(tc,|z|,e). PV: o=fma(p,S,o).
// tc pinned to SGPRs (readfirstlane); j-tiles staged in LDS (32KB) as f32.
// Fixed-bound softmax (j's independent); pure-f32 numerics (no f16 anywhere).
#define SCR(S, B)                                          \
    e0 = fmaf(tcr[B + 0], fabsf(S.x + xr[B + 0]), e0);     \
    e1 = fmaf(tcr[B + 1], fabsf(S.y + xr[B + 1]), e1);     \
    e2 = fmaf(tcr[B + 2], fabsf(S.z + xr[B + 2]), e2);     \
    e3 = fmaf(tcr[B + 3], fabsf(S.w + xr[B + 3]), e3);
#define PVC(S, B)                                          \
    o[B + 0] = fmaf(p, S.x, o[B + 0]);                     \
    o[B + 1] = fmaf(p, S.y, o[B + 1]);                     \
    o[B + 2] = fmaf(p, S.z, o[B + 2]);                     \
    o[B + 3] = fmaf(p, S.w, o[B + 3]);

__global__ __launch_bounds__(256) void k_attn(
    const float* __restrict__ xlf, const float* __restrict__ xrf,
    const float* __restrict__ u, const float* __restrict__ bound,
    const float* __restrict__ att,
    float* __restrict__ P, float* __restrict__ lb, int jlen)
{
    __shared__ __align__(16) float4 s_xf[2048];   // 256 j-rows x 8 float4 = 32KB
    __shared__ float s_u[256];
    const int tid = threadIdx.x;
    const int t128 = blockIdx.x & 127, part = blockIdx.x >> 7;
    const int bh = t128 >> 3;
    const int h  = bh & (H_ - 1);
    const int row = bh * N_ + (t128 & 7) * 256 + tid;

    // wave-uniform score coefficients pinned to SGPRs (v_fma takes 1 sgpr)
    float tcr[32];
    #pragma unroll
    for (int d = 0; d < 32; d++)
        tcr[d] = __builtin_bit_cast(float, __builtin_amdgcn_readfirstlane(
            __builtin_bit_cast(unsigned int, 0.4f * LOG2E * att[h * D_ + d])));

    float xr[32];
    {
        const float4* s = (const float4*)(xrf + (size_t)row * D_);
        #pragma unroll
        for (int q = 0; q < 8; q++) {
            const float4 v = s[q];
            xr[4 * q]     = v.x;
            xr[4 * q + 1] = v.y;
            xr[4 * q + 2] = v.z;
            xr[4 * q + 3] = v.w;
        }
    }
    const float negb = -bound[row];

    float l = 0.f;
    float o[32];
    #pragma unroll
    for (int k = 0; k < 32; k++) o[k] = 0.f;

    const float4* gx = (const float4*)(xlf + (size_t)bh * N_ * D_);  // 8/row
    const float* u_b = u + (size_t)bh * N_;

    const int jbeg = part * jlen;
    for (int jt = 0; jt < jlen; jt += 256) {
        if (jt) __syncthreads();
        const int j0 = jbeg + jt;
        #pragma unroll
        for (int k = 0; k < 8; k++)
            s_xf[tid + 256 * k] = gx[(size_t)j0 * 8 + tid + 256 * k];
        s_u[tid] = u_b[j0 + tid];
        __syncthreads();

        for (int j = 0; j < 256; j++) {
            const float4 S0 = s_xf[8 * j + 0], S1 = s_xf[8 * j + 1];
            const float4 S2 = s_xf[8 * j + 2], S3 = s_xf[8 * j + 3];
            const float4 S4 = s_xf[8 * j + 4], S5 = s_xf[8 * j + 5];
            const float4 S6 = s_xf[8 * j + 6], S7 = s_xf[8 * j + 7];
            float e0 = s_u[j] + negb, e1 = 0.f, e2 = 0.f, e3 = 0.f;
            SCR(S0, 0)  SCR(S1, 4)  SCR(S2, 8)  SCR(S3, 12)
            SCR(S4, 16) SCR(S5, 20) SCR(S6, 24) SCR(S7, 28)
            const float p = EXP2((e0 + e1) + (e2 + e3));
            l += p;
            PVC(S0, 0)  PVC(S1, 4)  PVC(S2, 8)  PVC(S3, 12)
            PVC(S4, 16) PVC(S5, 20) PVC(S6, 24) PVC(S7, 28)
        }
    }

    float* Pp = P + (size_t)part * M_ + (size_t)row * D_;
    #pragma unroll
    for (int k = 0; k < 8; k++) {
        float4 w;
        w.x = o[4*k]; w.y = o[4*k+1]; w.z = o[4*k+2]; w.w = o[4*k+3];
        ((float4*)Pp)[k] = w;
    }
    lb[part * ROWS_ + row] = l;
}

// Fused: merge JS partials (shared bound -> sum(o)/sum(l)) + bias + LN(128)
// (+optional ReLU). One 64-thread block per node row (b,n).
template <int JS>
__global__ __launch_bounds__(64) void k_comb_ln(
    const float* __restrict__ P, const float* __restrict__ lb,
    const float* __restrict__ bias, const float* __restrict__ g,
    const float* __restrict__ bta, float* __restrict__ outp, int do_relu)
{
    const int row = blockIdx.x;                    // b*N+n
    const int b = row >> 11, n = row & (N_ - 1);
    const int t = threadIdx.x;
    const int c0 = t, c1 = t + 64;
    const int bh0 = b * H_ + (c0 >> 5), bh1 = b * H_ + (c1 >> 5);
    const size_t i0 = ((size_t)bh0 * N_ + n) * D_ + (c0 & 31);
    const size_t i1 = ((size_t)bh1 * N_ + n) * D_ + (c1 & 31);
    float a0 = 0.f, a1 = 0.f, L0 = 0.f, L1 = 0.f;
    #pragma unroll
    for (int s = 0; s < JS; s++) {
        a0 += P[(size_t)s * M_ + i0];
        a1 += P[(size_t)s * M_ + i1];
        L0 += lb[s * ROWS_ + bh0 * N_ + n];
        L1 += lb[s * ROWS_ + bh1 * N_ + n];
    }
    const float x0 = a0 / L0 + bias[c0];
    const float x1 = a1 / L1 + bias[c1];
    float s = x0 + x1;
    #pragma unroll
    for (int w = 1; w < 64; w <<= 1) s += __shfl_xor(s, w);
    const float mu = s * (1.f / 128.f);
    const float d0 = x0 - mu, d1 = x1 - mu;
    float q = d0 * d0 + d1 * d1;
    #pragma unroll
    for (int w = 1; w < 64; w <<= 1) q += __shfl_xor(q, w);
    const float rstd = rsqrtf(q * (1.f / 128.f) + 1e-5f);
    float y0 = d0 * rstd * g[c0] + bta[c0];
    float y1 = d1 * rstd * g[c1] + bta[c1];
    if (do_relu) { y0 = fmaxf(y0, 0.f); y1 = fmaxf(y1, 0.f); }
    outp[(size_t)row * HD_ + c0] = y0;
    outp[(size_t)row * HD_ + c1] = y1;
}

extern "C" void kernel_launch(void* const* d_in, const int* in_sizes, int n_in,
                              void* d_out, int out_size, void* d_ws, size_t ws_size,
                              hipStream_t stream) {
    const float* x    = (const float*)d_in[0];
    const float* Wl1  = (const float*)d_in[2];
    const float* bl1  = (const float*)d_in[3];
    const float* Wr1  = (const float*)d_in[4];
    const float* br1  = (const float*)d_in[5];
    const float* att1 = (const float*)d_in[6];
    const float* bias1= (const float*)d_in[7];
    const float* ln1g = (const float*)d_in[8];
    const float* ln1b = (const float*)d_in[9];
    const float* Wl2  = (const float*)d_in[10];
    const float* bl2  = (const float*)d_in[11];
    const float* Wr2  = (const float*)d_in[12];
    const float* br2  = (const float*)d_in[13];
    const float* att2 = (const float*)d_in[14];
    const float* bias2= (const float*)d_in[15];
    const float* ln2g = (const float*)d_in[16];
    const float* ln2b = (const float*)d_in[17];

    float* ws = (float*)d_ws;
    float* xl  = ws;                       // M_ f32
    float* xrf = xl + M_;                  // M_ f32
    float* u     = xrf + M_;               // ROWS_
    float* bound = u + ROWS_;              // ROWS_

    // j-split: largest fitting. floats = 2M + 2R + js*(M+R) + M (h slab)
    int js = 1;
    for (int cand = 8; cand >= 1; cand >>= 1) {
        const size_t need = ((size_t)3 * M_ + 2 * ROWS_
                             + (size_t)cand * (M_ + ROWS_)) * sizeof(float);
        if (ws_size >= need) { js = cand; break; }
    }
    const int jlen = N_ / js;

    float* P  = bound + ROWS_;             // js * M_
    float* lb = P + (size_t)js * M_;       // js * ROWS_
    float* h  = lb + (size_t)js * ROWS_;   // M_ (dedicated slab)
    float* outf = (float*)d_out;

    const int BN = B_ * N_;                // 8192
    // ---- layer 1 ----
    k_linear<<<BN / 32, 256, 0, stream>>>(x, Wl1, bl1, Wr1, br1, xl, xrf, 32);
    k_u<<<ROWS_ / 256, 256, 0, stream>>>(xl, att1, u);
    k_bound<<<BH_, 512, 0, stream>>>(xl, xrf, u, att1, bound);
    k_attn<<<128 * js, 256, 0, stream>>>(xl, xrf, u, bound, att1, P, lb, jlen);
    if      (js == 8) k_comb_ln<8><<<BN, 64, 0, stream>>>(P, lb, bias1, ln1g, ln1b, h, 1);
    else if (js == 4) k_comb_ln<4><<<BN, 64, 0, stream>>>(P, lb, bias1, ln1g, ln1b, h, 1);
    else if (js == 2) k_comb_ln<2><<<BN, 64, 0, stream>>>(P, lb, bias1, ln1g, ln1b, h, 1);
    else              k_comb_ln<1><<<BN, 64, 0, stream>>>(P, lb, bias1, ln1g, ln1b, h, 1);
    // ---- layer 2 ----
    k_linear<<<BN / 32, 256, 0, stream>>>(h, Wl2, bl2, Wr2, br2, xl, xrf, 128);
    k_u<<<ROWS_ / 256, 256, 0, stream>>>(xl, att2, u);
    k_bound<<<BH_, 512, 0, stream>>>(xl, xrf, u, att2, bound);
    k_attn<<<128 * js, 256, 0, stream>>>(xl, xrf, u, bound, att2, P, lb, jlen);
    if      (js == 8) k_comb_ln<8><<<BN, 64, 0, stream>>>(P, lb, bias2, ln2g, ln2b, outf, 0);
    else if (js == 4) k_comb_ln<4><<<BN, 64, 0, stream>>>(P, lb, bias2, ln2g, ln2b, outf, 0);
    else if (js == 2) k_comb_ln<2><<<BN, 64, 0, stream>>>(P, lb, bias2, ln2g, ln2b, outf, 0);
    else              k_comb_ln<1><<<BN, 64, 0, stream>>>(P, lb, bias2, ln2g, ln2b, outf, 0);
}

// Round 23
// 568.029 us; speedup vs baseline: 1.1242x; 1.1242x over previous
//
#include <hip/hip_runtime.h>
#include <math.h>

#define LOG2E 1.4426950408889634f

#if __has_builtin(__builtin_amdgcn_exp2f)
#define EXP2(x) __builtin_amdgcn_exp2f(x)
#else
#define EXP2(x) exp2f(x)
#endif

constexpr int B_ = 4, N_ = 2048, H_ = 4, D_ = 32, HD_ = 128;
constexpr int BH_ = B_ * H_;          // 16
constexpr int ROWS_ = BH_ * N_;       // 32768
constexpr size_t M_ = (size_t)ROWS_ * D_;  // 1,048,576 floats

// x[BN,K] @ Wl/Wr[K,128] + bl/br -> xl, xrf (both f32 [bh][n][d])
__global__ __launch_bounds__(256) void k_linear(
    const float* __restrict__ x,
    const float* __restrict__ Wl, const float* __restrict__ bl,
    const float* __restrict__ Wr, const float* __restrict__ br,
    float* __restrict__ xl, float* __restrict__ xrf, int K)
{
    __shared__ __align__(16) float xs[32 * 128];
    const int tid = threadIdx.x;
    const int r0 = blockIdx.x * 32;
    const float4* src = (const float4*)(x + (size_t)r0 * K);
    float4* dst = (float4*)xs;
    for (int idx = tid; idx < 8 * K; idx += 256) dst[idx] = src[idx];
    __syncthreads();

    const int c  = tid & 127;
    const int rg = tid >> 7;
    float accl[16], accr[16];
    const float blv = bl[c], brv = br[c];
    #pragma unroll
    for (int r = 0; r < 16; r++) { accl[r] = blv; accr[r] = brv; }
    #pragma unroll 8
    for (int k = 0; k < K; k++) {
        const float wl = Wl[k * HD_ + c];
        const float wr = Wr[k * HD_ + c];
        #pragma unroll
        for (int r = 0; r < 16; r++) {
            const float xv = xs[(rg * 16 + r) * K + k];
            accl[r] = fmaf(xv, wl, accl[r]);
            accr[r] = fmaf(xv, wr, accr[r]);
        }
    }
    const int h = c >> 5, d = c & 31;
    #pragma unroll
    for (int r = 0; r < 16; r++) {
        const int row = r0 + rg * 16 + r;
        const int b = row >> 11, n = row & (N_ - 1);
        const size_t o = (((size_t)(b * H_ + h)) * N_ + n) * D_ + d;
        xl[o] = accl[r];
        xrf[o] = accr[r];
    }
}

// u_j = 0.6*log2e * att_h . xl_j  (target-side term cancels in softmax)
__global__ __launch_bounds__(256) void k_u(
    const float* __restrict__ xl, const float* __restrict__ att,
    float* __restrict__ u)
{
    const int idx = blockIdx.x * 256 + threadIdx.x; // [0, ROWS_)
    const int h = (idx / N_) & (H_ - 1);
    const float4* a4 = (const float4*)(att + h * D_);
    const float4* l4 = (const float4*)(xl + (size_t)idx * D_);
    float su = 0.f;
    #pragma unroll
    for (int q = 0; q < 8; q++) {
        const float4 a = a4[q], lv = l4[q];
        su += a.x * lv.x + a.y * lv.y + a.z * lv.z + a.w * lv.w;
    }
    u[idx] = 0.6f * LOG2E * su;
}

// Per-row sound upper bound on e (log2 domain), all f32:
// bound_i = umax + sum_d |tc_d| (max_j|xl_jd| + |xr_id|) + slack.
__global__ __launch_bounds__(512) void k_bound(
    const float* __restrict__ xl, const float* __restrict__ xrf,
    const float* __restrict__ u, const float* __restrict__ att,
    float* __restrict__ bound)
{
    __shared__ float tca[32];
    __shared__ float redA[32][17];
    __shared__ float clv[32];
    __shared__ float redu[512];
    const int bh = blockIdx.x, h = bh & (H_ - 1), t = threadIdx.x;

    if (t < 32) tca[t] = fabsf(0.4f * LOG2E * att[h * D_ + t]);

    // cl_d = max_j |xl_jd|
    const float* xb = xl + (size_t)bh * N_ * D_;
    const int p = t & 31, rg = t >> 5;            // 32 dims x 16 row-groups
    float m0 = 0.f;
    for (int r = rg; r < N_; r += 16)
        m0 = fmaxf(m0, fabsf(xb[r * D_ + p]));
    redA[p][rg] = m0;
    // umax
    const float* ub = u + (size_t)bh * N_;
    float um = -1e30f;
    for (int r = t; r < N_; r += 512) um = fmaxf(um, ub[r]);
    redu[t] = um;
    __syncthreads();
    if (t < 32) {
        float a = 0.f;
        for (int g = 0; g < 16; g++) a = fmaxf(a, redA[t][g]);
        clv[t] = a;
    }
    for (int s = 256; s > 0; s >>= 1) {
        if (t < s) redu[t] = fmaxf(redu[t], redu[t + s]);
        __syncthreads();
    }
    const float umax = redu[0];
    const float* xrb = xrf + (size_t)bh * N_ * D_;
    for (int r = t; r < N_; r += 512) {
        float s = 0.f;
        #pragma unroll
        for (int k = 0; k < 32; k++)
            s = fmaf(tca[k], clv[k] + fabsf(xrb[r * D_ + k]), s);
        bound[bh * N_ + r] = umax + s + 0.25f;
    }
}

// ALL-F32 flash GATv2 attention, NO LDS. R22 post-mortem: wave-uniform
// ds_read_b128 costs ~12cyc of the per-CU LDS unit regardless of being a
// broadcast; with the allocator re-reading the tile (VGPR 80 < ~110 live),
// LDS cycles = 16 reads/j x 16 waves x 256 j x 12cyc = 328us = measured.
// f32 tiles have a hard ~164us/dispatch LDS floor even single-read.
// Fix: read the uniform j-stream STRAIGHT FROM GLOBAL (L1/L2 broadcast;
// xl is 4MB, L2-resident, BW trivial). Allocator-robust: if it re-issues
// the 8 loads for PV, that's ~8 issue slots + hidden L2 latency, not 96
// cycles of the shared LDS unit. Math identical to R22 (passed, 0.0156).
#define SCR(S, B)                                          \
    e0 = fmaf(tcr[B + 0], fabsf(S.x + xr[B + 0]), e0);     \
    e1 = fmaf(tcr[B + 1], fabsf(S.y + xr[B + 1]), e1);     \
    e2 = fmaf(tcr[B + 2], fabsf(S.z + xr[B + 2]), e2);     \
    e3 = fmaf(tcr[B + 3], fabsf(S.w + xr[B + 3]), e3);
#define PVC(S, B)                                          \
    o[B + 0] = fmaf(p, S.x, o[B + 0]);                     \
    o[B + 1] = fmaf(p, S.y, o[B + 1]);                     \
    o[B + 2] = fmaf(p, S.z, o[B + 2]);                     \
    o[B + 3] = fmaf(p, S.w, o[B + 3]);

__global__ __launch_bounds__(256) void k_attn(
    const float* __restrict__ xlf, const float* __restrict__ xrf,
    const float* __restrict__ u, const float* __restrict__ bound,
    const float* __restrict__ att,
    float* __restrict__ P, float* __restrict__ lb, int jlen)
{
    const int tid = threadIdx.x;
    const int t128 = blockIdx.x & 127, part = blockIdx.x >> 7;
    const int bh = t128 >> 3;
    const int h  = bh & (H_ - 1);
    const int row = bh * N_ + (t128 & 7) * 256 + tid;

    // wave-uniform score coefficients pinned to SGPRs (v_fma takes 1 sgpr)
    float tcr[32];
    #pragma unroll
    for (int d = 0; d < 32; d++)
        tcr[d] = __builtin_bit_cast(float, __builtin_amdgcn_readfirstlane(
            __builtin_bit_cast(unsigned int, 0.4f * LOG2E * att[h * D_ + d])));

    float xr[32];
    {
        const float4* s = (const float4*)(xrf + (size_t)row * D_);
        #pragma unroll
        for (int q = 0; q < 8; q++) {
            const float4 v = s[q];
            xr[4 * q]     = v.x;
            xr[4 * q + 1] = v.y;
            xr[4 * q + 2] = v.z;
            xr[4 * q + 3] = v.w;
        }
    }
    const float negb = -bound[row];

    float l = 0.f;
    float o[32];
    #pragma unroll
    for (int k = 0; k < 32; k++) o[k] = 0.f;

    const float4* gx = (const float4*)(xlf + (size_t)bh * N_ * D_);  // 8/row
    const float* u_b = u + (size_t)bh * N_;

    const int jbeg = part * jlen, jend = jbeg + jlen;
    for (int j = jbeg; j < jend; j++) {
        const float4 S0 = gx[8 * j + 0], S1 = gx[8 * j + 1];
        const float4 S2 = gx[8 * j + 2], S3 = gx[8 * j + 3];
        const float4 S4 = gx[8 * j + 4], S5 = gx[8 * j + 5];
        const float4 S6 = gx[8 * j + 6], S7 = gx[8 * j + 7];
        float e0 = u_b[j] + negb, e1 = 0.f, e2 = 0.f, e3 = 0.f;
        SCR(S0, 0)  SCR(S1, 4)  SCR(S2, 8)  SCR(S3, 12)
        SCR(S4, 16) SCR(S5, 20) SCR(S6, 24) SCR(S7, 28)
        const float p = EXP2((e0 + e1) + (e2 + e3));
        l += p;
        PVC(S0, 0)  PVC(S1, 4)  PVC(S2, 8)  PVC(S3, 12)
        PVC(S4, 16) PVC(S5, 20) PVC(S6, 24) PVC(S7, 28)
    }

    float* Pp = P + (size_t)part * M_ + (size_t)row * D_;
    #pragma unroll
    for (int k = 0; k < 8; k++) {
        float4 w;
        w.x = o[4*k]; w.y = o[4*k+1]; w.z = o[4*k+2]; w.w = o[4*k+3];
        ((float4*)Pp)[k] = w;
    }
    lb[part * ROWS_ + row] = l;
}

// Fused: merge JS partials (shared bound -> sum(o)/sum(l)) + bias + LN(128)
// (+optional ReLU). One 64-thread block per node row (b,n).
template <int JS>
__global__ __launch_bounds__(64) void k_comb_ln(
    const float* __restrict__ P, const float* __restrict__ lb,
    const float* __restrict__ bias, const float* __restrict__ g,
    const float* __restrict__ bta, float* __restrict__ outp, int do_relu)
{
    const int row = blockIdx.x;                    // b*N+n
    const int b = row >> 11, n = row & (N_ - 1);
    const int t = threadIdx.x;
    const int c0 = t, c1 = t + 64;
    const int bh0 = b * H_ + (c0 >> 5), bh1 = b * H_ + (c1 >> 5);
    const size_t i0 = ((size_t)bh0 * N_ + n) * D_ + (c0 & 31);
    const size_t i1 = ((size_t)bh1 * N_ + n) * D_ + (c1 & 31);
    float a0 = 0.f, a1 = 0.f, L0 = 0.f, L1 = 0.f;
    #pragma unroll
    for (int s = 0; s < JS; s++) {
        a0 += P[(size_t)s * M_ + i0];
        a1 += P[(size_t)s * M_ + i1];
        L0 += lb[s * ROWS_ + bh0 * N_ + n];
        L1 += lb[s * ROWS_ + bh1 * N_ + n];
    }
    const float x0 = a0 / L0 + bias[c0];
    const float x1 = a1 / L1 + bias[c1];
    float s = x0 + x1;
    #pragma unroll
    for (int w = 1; w < 64; w <<= 1) s += __shfl_xor(s, w);
    const float mu = s * (1.f / 128.f);
    const float d0 = x0 - mu, d1 = x1 - mu;
    float q = d0 * d0 + d1 * d1;
    #pragma unroll
    for (int w = 1; w < 64; w <<= 1) q += __shfl_xor(q, w);
    const float rstd = rsqrtf(q * (1.f / 128.f) + 1e-5f);
    float y0 = d0 * rstd * g[c0] + bta[c0];
    float y1 = d1 * rstd * g[c1] + bta[c1];
    if (do_relu) { y0 = fmaxf(y0, 0.f); y1 = fmaxf(y1, 0.f); }
    outp[(size_t)row * HD_ + c0] = y0;
    outp[(size_t)row * HD_ + c1] = y1;
}

extern "C" void kernel_launch(void* const* d_in, const int* in_sizes, int n_in,
                              void* d_out, int out_size, void* d_ws, size_t ws_size,
                              hipStream_t stream) {
    const float* x    = (const float*)d_in[0];
    const float* Wl1  = (const float*)d_in[2];
    const float* bl1  = (const float*)d_in[3];
    const float* Wr1  = (const float*)d_in[4];
    const float* br1  = (const float*)d_in[5];
    const float* att1 = (const float*)d_in[6];
    const float* bias1= (const float*)d_in[7];
    const float* ln1g = (const float*)d_in[8];
    const float* ln1b = (const float*)d_in[9];
    const float* Wl2  = (const float*)d_in[10];
    const float* bl2  = (const float*)d_in[11];
    const float* Wr2  = (const float*)d_in[12];
    const float* br2  = (const float*)d_in[13];
    const float* att2 = (const float*)d_in[14];
    const float* bias2= (const float*)d_in[15];
    const float* ln2g = (const float*)d_in[16];
    const float* ln2b = (const float*)d_in[17];

    float* ws = (float*)d_ws;
    float* xl  = ws;                       // M_ f32
    float* xrf = xl + M_;                  // M_ f32
    float* u     = xrf + M_;               // ROWS_
    float* bound = u + ROWS_;              // ROWS_

    // j-split: largest fitting. floats = 2M + 2R + js*(M+R) + M (h slab)
    int js = 1;
    for (int cand = 8; cand >= 1; cand >>= 1) {
        const size_t need = ((size_t)3 * M_ + 2 * ROWS_
                             + (size_t)cand * (M_ + ROWS_)) * sizeof(float);
        if (ws_size >= need) { js = cand; break; }
    }
    const int jlen = N_ / js;

    float* P  = bound + ROWS_;             // js * M_
    float* lb = P + (size_t)js * M_;       // js * ROWS_
    float* h  = lb + (size_t)js * ROWS_;   // M_ (dedicated slab)
    float* outf = (float*)d_out;

    const int BN = B_ * N_;                // 8192
    // ---- layer 1 ----
    k_linear<<<BN / 32, 256, 0, stream>>>(x, Wl1, bl1, Wr1, br1, xl, xrf, 32);
    k_u<<<ROWS_ / 256, 256, 0, stream>>>(xl, att1, u);
    k_bound<<<BH_, 512, 0, stream>>>(xl, xrf, u, att1, bound);
    k_attn<<<128 * js, 256, 0, stream>>>(xl, xrf, u, bound, att1, P, lb, jlen);
    if      (js == 8) k_comb_ln<8><<<BN, 64, 0, stream>>>(P, lb, bias1, ln1g, ln1b, h, 1);
    else if (js == 4) k_comb_ln<4><<<BN, 64, 0, stream>>>(P, lb, bias1, ln1g, ln1b, h, 1);
    else if (js == 2) k_comb_ln<2><<<BN, 64, 0, stream>>>(P, lb, bias1, ln1g, ln1b, h, 1);
    else              k_comb_ln<1><<<BN, 64, 0, stream>>>(P, lb, bias1, ln1g, ln1b, h, 1);
    // ---- layer 2 ----
    k_linear<<<BN / 32, 256, 0, stream>>>(h, Wl2, bl2, Wr2, br2, xl, xrf, 128);
    k_u<<<ROWS_ / 256, 256, 0, stream>>>(xl, att2, u);
    k_bound<<<BH_, 512, 0, stream>>>(xl, xrf, u, att2, bound);
    k_attn<<<128 * js, 256, 0, stream>>>(xl, xrf, u, bound, att2, P, lb, jlen);
    if      (js == 8) k_comb_ln<8><<<BN, 64, 0, stream>>>(P, lb, bias2, ln2g, ln2b, outf, 0);
    else if (js == 4) k_comb_ln<4><<<BN, 64, 0, stream>>>(P, lb, bias2, ln2g, ln2b, outf, 0);
    else if (js == 2) k_comb_ln<2><<<BN, 64, 0, stream>>>(P, lb, bias2, ln2g, ln2b, outf, 0);
    else              k_comb_ln<1><<<BN, 64, 0, stream>>>(P, lb, bias2, ln2g, ln2b, outf, 0);
}